// Round 1
// baseline (4364.143 us; speedup 1.0000x reference)
//
#include <hip/hip_runtime.h>
#include <math.h>

// Problem constants (CustomRNN_1511828488500)
#define Bb 128   // batch
#define Tt 256   // seq len
#define Dd 256   // input dim
#define Hh 256   // hidden dim
// L = 2 layers, bidirectional; backward direction only needs ONE step (see analysis)

// GEMM tile config: C tile 32x64, 256 threads, 2x4 micro-tile, K-chunk 32.
#define TM 32
#define TN 64
#define KC 32

// Computes, for one 32x64 tile of a [128 x 256] output:
//   C = [pair1: A1(128xK=256) @ B1(256x256)] + [pair2: A2 @ B2] + Zadd + bias, optional tanh.
// Either pair may be skipped by passing A==nullptr (uniform across block).
// B matrices are row-major [K=256][N=256] (ldb = 256).
__device__ __forceinline__ void gemm_tile(
    int tile,
    const float* __restrict__ A1, int lda1,
    const float* __restrict__ B1,
    const float* __restrict__ A2, int lda2,
    const float* __restrict__ B2,
    const float* __restrict__ Zadd,   // [128][256] pre-computed addend, or nullptr
    const float* __restrict__ bias,   // [256] or nullptr
    float* __restrict__ Cout,         // [128][256]
    int dotanh)
{
    __shared__ float As[TM][KC + 1];  // +1 pad: conflict-free column reads
    __shared__ float Bs[KC][TN];      // rows of 64 floats: 2-way (free) / broadcast reads

    const int tid = threadIdx.x;      // 256 threads
    const int tx = tid & 15;          // 16 col groups * 4 cols
    const int ty = tid >> 4;          // 16 row groups * 2 rows
    const int m0 = (tile >> 2) * TM;  // 4 M-tiles
    const int n0 = (tile & 3) * TN;   // 4 N-tiles

    float acc[2][4];
#pragma unroll
    for (int i = 0; i < 2; i++)
#pragma unroll
        for (int j = 0; j < 4; j++) acc[i][j] = 0.f;

    for (int pair = 0; pair < 2; ++pair) {
        const float* Ap = pair ? A2 : A1;
        const float* Bp = pair ? B2 : B1;
        const int lda = pair ? lda2 : lda1;
        if (!Ap) continue;  // uniform: kernel-arg derived

        for (int k0 = 0; k0 < 256; k0 += KC) {
            // Stage A: 32 rows x 32 k. tid: k = tid&31 (coalesced 128B runs), m = tid>>5 (+8/iter)
#pragma unroll
            for (int i = 0; i < 4; i++) {
                const int m = (tid >> 5) + i * 8;
                As[m][tid & 31] = Ap[(size_t)(m0 + m) * lda + k0 + (tid & 31)];
            }
            // Stage B: 32 k x 64 n. tid: n = tid&63 (coalesced), k = tid>>6 (+4/iter)
#pragma unroll
            for (int i = 0; i < 8; i++) {
                const int k = (tid >> 6) + i * 4;
                Bs[k][tid & 63] = Bp[(size_t)(k0 + k) * Hh + n0 + (tid & 63)];
            }
            __syncthreads();
#pragma unroll
            for (int kk = 0; kk < KC; kk++) {
                const float a0 = As[ty * 2 + 0][kk];
                const float a1 = As[ty * 2 + 1][kk];
                const float4 b = *(const float4*)&Bs[kk][tx * 4];
                acc[0][0] += a0 * b.x; acc[0][1] += a0 * b.y;
                acc[0][2] += a0 * b.z; acc[0][3] += a0 * b.w;
                acc[1][0] += a1 * b.x; acc[1][1] += a1 * b.y;
                acc[1][2] += a1 * b.z; acc[1][3] += a1 * b.w;
            }
            __syncthreads();
        }
    }

#pragma unroll
    for (int i = 0; i < 2; i++) {
        const int m = m0 + ty * 2 + i;
#pragma unroll
        for (int j = 0; j < 4; j++) {
            const int n = n0 + tx * 4 + j;
            float v = acc[i][j];
            if (Zadd) v += Zadd[(size_t)m * Hh + n];
            if (bias) v += bias[n];
            if (dotanh) v = tanhf(v);
            Cout[(size_t)m * Hh + n] = v;
        }
    }
}

// Phase A (parallel over t): Z0[t] = x[:,t,:] @ Wih_f[0,t] + b_f[0,t]   (no tanh)
__global__ void k_z0(const float* __restrict__ x, const float* __restrict__ Wih_f,
                     const float* __restrict__ b_f, float* __restrict__ Z0) {
    const int t = blockIdx.y;
    gemm_tile(blockIdx.x,
              x + (size_t)t * Dd, Tt * Dd,          // A: x[b][t][:], row stride T*D
              Wih_f + (size_t)t * Dd * Hh,          // Wih_f[0][t]
              nullptr, 0, nullptr,
              nullptr,
              b_f + (size_t)t * Hh,                 // b_f[0][t]
              Z0 + (size_t)t * Bb * Hh, 0);
}

// Backward direction: exactly one step at t = T-1 from h=0 (Whh terms vanish).
__global__ void k_back0(const float* __restrict__ x, const float* __restrict__ Wih_b,
                        const float* __restrict__ b_b, float* __restrict__ hb0) {
    gemm_tile(blockIdx.x,
              x + (size_t)(Tt - 1) * Dd, Tt * Dd,
              Wih_b + (size_t)(Tt - 1) * Dd * Hh,       // Wih_b[0][T-1]
              nullptr, 0, nullptr,
              nullptr,
              b_b + (size_t)(Tt - 1) * Hh,              // b_b[0][T-1]
              hb0, 1);
}
__global__ void k_back1(const float* __restrict__ hb0, const float* __restrict__ Wih_b,
                        const float* __restrict__ b_b, float* __restrict__ hb1) {
    gemm_tile(blockIdx.x,
              hb0, Hh,
              Wih_b + (size_t)(Tt + Tt - 1) * Dd * Hh,  // Wih_b[1][T-1]
              nullptr, 0, nullptr,
              nullptr,
              b_b + (size_t)(Tt + Tt - 1) * Hh,         // b_b[1][T-1]
              hb1, 1);
}

// Serial 3-stage skewed pipeline, one launch per s = 0..T+1:
//  roleA (s in [0,T-1]):  h0(s)   = tanh(Z0[s] + h0(s-1) @ Whh_f[0][s])
//  roleB (s in [1,T]):    P(s-1)  = h0(s-1) @ Wih_f[1][s-1] + b_f[1][s-1]
//  roleC (s in [2,T+1]):  h1(s-2) = tanh(P(s-2) + h1(s-3) @ Whh_f[1][s-2])
// P and h1 are 2-deep ping-pong buffers (written at s, read at s+1).
__global__ void k_step(int s,
                       const float* __restrict__ Whh_f, const float* __restrict__ Wih_f,
                       const float* __restrict__ b_f,
                       const float* __restrict__ Z0, float* __restrict__ h0_all,
                       float* __restrict__ Pbuf, float* __restrict__ h1buf) {
    const int role = blockIdx.y;
    if (role == 0) {
        if (s >= Tt) return;
        gemm_tile(blockIdx.x,
                  (s > 0) ? h0_all + (size_t)(s - 1) * Bb * Hh : nullptr, Hh,
                  Whh_f + (size_t)s * Hh * Hh,                 // Whh_f[0][s]
                  nullptr, 0, nullptr,
                  Z0 + (size_t)s * Bb * Hh,
                  nullptr,
                  h0_all + (size_t)s * Bb * Hh, 1);
    } else if (role == 1) {
        if (s < 1 || s > Tt) return;
        const int t = s - 1;
        gemm_tile(blockIdx.x,
                  h0_all + (size_t)t * Bb * Hh, Hh,
                  Wih_f + (size_t)(Tt + t) * Dd * Hh,          // Wih_f[1][t]
                  nullptr, 0, nullptr,
                  nullptr,
                  b_f + (size_t)(Tt + t) * Hh,                 // b_f[1][t]
                  Pbuf + (size_t)(t & 1) * Bb * Hh, 0);
    } else {
        if (s < 2) return;
        const int t = s - 2;
        gemm_tile(blockIdx.x,
                  (t > 0) ? h1buf + (size_t)((t + 1) & 1) * Bb * Hh : nullptr, Hh,
                  Whh_f + (size_t)(Tt + t) * Hh * Hh,          // Whh_f[1][t]
                  nullptr, 0, nullptr,
                  Pbuf + (size_t)(t & 1) * Bb * Hh,
                  nullptr,
                  h1buf + (size_t)(t & 1) * Bb * Hh, 1);
    }
}

// out[b][h] = sum_{j<256} h1fin[b][j]*fc_w[h][j] + sum_{j<256} hb1[b][j]*fc_w[h][256+j] + fc_b[h]
__global__ void k_fc(const float* __restrict__ h1fin, const float* __restrict__ hb1,
                     const float* __restrict__ fcw, const float* __restrict__ fcb,
                     float* __restrict__ out) {
    const int b = blockIdx.x;
    const int h = threadIdx.x;  // 256
    __shared__ float last[2 * Hh];
    last[h] = h1fin[(size_t)b * Hh + h];
    last[Hh + h] = hb1[(size_t)b * Hh + h];
    __syncthreads();
    float acc = fcb[h];
    const float* wrow = fcw + (size_t)h * (2 * Hh);
#pragma unroll 4
    for (int j = 0; j < 2 * Hh; j++) acc += last[j] * wrow[j];
    out[(size_t)b * Hh + h] = acc;
}

extern "C" void kernel_launch(void* const* d_in, const int* in_sizes, int n_in,
                              void* d_out, int out_size, void* d_ws, size_t ws_size,
                              hipStream_t stream) {
    const float* x     = (const float*)d_in[0];
    const float* Wih_f = (const float*)d_in[1];
    const float* Whh_f = (const float*)d_in[2];
    const float* b_f   = (const float*)d_in[3];
    const float* Wih_b = (const float*)d_in[4];
    // d_in[5] = Whh_b: provably unused (backward contributes only its first step from h=0)
    const float* b_b   = (const float*)d_in[6];
    const float* fc_w  = (const float*)d_in[7];
    const float* fc_b  = (const float*)d_in[8];
    float* out = (float*)d_out;

    // Workspace layout (floats): Z0[T*B*H] | h0_all[T*B*H] | Pbuf[2*B*H] | h1buf[2*B*H] | hb0 | hb1
    float* ws     = (float*)d_ws;
    float* Z0     = ws;
    float* h0_all = Z0 + (size_t)Tt * Bb * Hh;
    float* Pbuf   = h0_all + (size_t)Tt * Bb * Hh;
    float* h1buf  = Pbuf + (size_t)2 * Bb * Hh;
    float* hb0    = h1buf + (size_t)2 * Bb * Hh;
    float* hb1    = hb0 + (size_t)Bb * Hh;
    // total = 2*T*B*H + 6*B*H floats = ~67.9 MB

    dim3 blk(256);
    // Parallel prologue: Z0 for all t (4096 WGs), backward one-step (2 tiny launches)
    hipLaunchKernelGGL(k_z0, dim3(16, Tt), blk, 0, stream, x, Wih_f, b_f, Z0);
    hipLaunchKernelGGL(k_back0, dim3(16), blk, 0, stream, x, Wih_b, b_b, hb0);
    hipLaunchKernelGGL(k_back1, dim3(16), blk, 0, stream, hb0, Wih_b, b_b, hb1);
    // Serial skewed chain: T+2 launches, stream order provides inter-step sync
    for (int s = 0; s <= Tt + 1; ++s)
        hipLaunchKernelGGL(k_step, dim3(16, 3), blk, 0, stream,
                           s, Whh_f, Wih_f, b_f, Z0, h0_all, Pbuf, h1buf);
    // h1(T-1) lives in h1buf[ (T-1)&1 ] = h1buf[1]
    hipLaunchKernelGGL(k_fc, dim3(Bb), blk, 0, stream,
                       h1buf + (size_t)1 * Bb * Hh, hb1, fc_w, fc_b, out);
}

// Round 2
// 4293.524 us; speedup vs baseline: 1.0164x; 1.0164x over previous
//
#include <hip/hip_runtime.h>
#include <math.h>

// Problem constants (CustomRNN_1511828488500)
#define Bb 128   // batch
#define Tt 256   // seq len
#define Dd 256   // input dim
#define Hh 256   // hidden dim
// L = 2 layers, bidirectional; backward direction only needs ONE step:
// out_b[:, -1] is the backward scan's step-0 output = one RNN step on x[:,T-1]
// from h0=0 (all Whh_b terms vanish; Whh_b is never read).

// ---------------------------------------------------------------------------
// Generic 32x64-tile fp32 GEMM helper (used by the parallel prologue kernels).
// ---------------------------------------------------------------------------
#define TM 32
#define TN 64
#define KC 32

__device__ __forceinline__ void gemm_tile(
    int tile,
    const float* __restrict__ A1, int lda1,
    const float* __restrict__ B1,
    const float* __restrict__ bias,
    float* __restrict__ Cout,
    int dotanh)
{
    __shared__ float As[TM][KC + 1];
    __shared__ float Bs[KC][TN];

    const int tid = threadIdx.x;      // 256 threads
    const int tx = tid & 15;
    const int ty = tid >> 4;
    const int m0 = (tile >> 2) * TM;
    const int n0 = (tile & 3) * TN;

    float acc[2][4];
#pragma unroll
    for (int i = 0; i < 2; i++)
#pragma unroll
        for (int j = 0; j < 4; j++) acc[i][j] = 0.f;

    for (int k0 = 0; k0 < 256; k0 += KC) {
#pragma unroll
        for (int i = 0; i < 4; i++) {
            const int m = (tid >> 5) + i * 8;
            As[m][tid & 31] = A1[(size_t)(m0 + m) * lda1 + k0 + (tid & 31)];
        }
#pragma unroll
        for (int i = 0; i < 8; i++) {
            const int k = (tid >> 6) + i * 4;
            Bs[k][tid & 63] = B1[(size_t)(k0 + k) * Hh + n0 + (tid & 63)];
        }
        __syncthreads();
#pragma unroll
        for (int kk = 0; kk < KC; kk++) {
            const float a0 = As[ty * 2 + 0][kk];
            const float a1 = As[ty * 2 + 1][kk];
            const float4 b = *(const float4*)&Bs[kk][tx * 4];
            acc[0][0] += a0 * b.x; acc[0][1] += a0 * b.y;
            acc[0][2] += a0 * b.z; acc[0][3] += a0 * b.w;
            acc[1][0] += a1 * b.x; acc[1][1] += a1 * b.y;
            acc[1][2] += a1 * b.z; acc[1][3] += a1 * b.w;
        }
        __syncthreads();
    }

#pragma unroll
    for (int i = 0; i < 2; i++) {
        const int m = m0 + ty * 2 + i;
#pragma unroll
        for (int j = 0; j < 4; j++) {
            const int n = n0 + tx * 4 + j;
            float v = acc[i][j];
            if (bias) v += bias[n];
            if (dotanh) v = tanhf(v);
            Cout[(size_t)m * Hh + n] = v;
        }
    }
}

// Phase A (parallel over t): Z0[t] = x[:,t,:] @ Wih_f[0,t] + b_f[0,t]
__global__ void k_z0(const float* __restrict__ x, const float* __restrict__ Wih_f,
                     const float* __restrict__ b_f, float* __restrict__ Z0) {
    const int t = blockIdx.y;
    gemm_tile(blockIdx.x,
              x + (size_t)t * Dd, Tt * Dd,
              Wih_f + (size_t)t * Dd * Hh,
              b_f + (size_t)t * Hh,
              Z0 + (size_t)t * Bb * Hh, 0);
}

// Backward direction: exactly one step at t = T-1 from h=0.
__global__ void k_back0(const float* __restrict__ x, const float* __restrict__ Wih_b,
                        const float* __restrict__ b_b, float* __restrict__ hb0) {
    gemm_tile(blockIdx.x,
              x + (size_t)(Tt - 1) * Dd, Tt * Dd,
              Wih_b + (size_t)(Tt - 1) * Dd * Hh,
              b_b + (size_t)(Tt - 1) * Hh,
              hb0, 1);
}
__global__ void k_back1(const float* __restrict__ hb0, const float* __restrict__ Wih_b,
                        const float* __restrict__ b_b, float* __restrict__ hb1) {
    gemm_tile(blockIdx.x,
              hb0, Hh,
              Wih_b + (size_t)(Tt + Tt - 1) * Dd * Hh,
              b_b + (size_t)(Tt + Tt - 1) * Hh,
              hb1, 1);
}

// ---------------------------------------------------------------------------
// Persistent serial chain: 48 WGs (16 per role), one device-scope barrier per
// timestep, per-WG register prefetch of next step's weight slice.
//  roleA (s in [0,T-1]):  h0(s)   = tanh(Z0[s] + h0(s-1) @ Whh_f[0][s])
//  roleB (s in [1,T]):    P(s-1)  = h0(s-1) @ Wih_f[1][s-1] + b_f[1][s-1]
//  roleC (s in [2,T+1]):  h1(s-2) = tanh(P(s-2) + h1(s-3) @ Whh_f[1][s-2])
// ---------------------------------------------------------------------------
#define GWG 48
#define NSTEP (Tt + 2)
#define AST_STRIDE 34          // padded [K][34] layout for conflict-free col writes
#define LDS_FLOATS (256 * AST_STRIDE + 256 * 64)   // Ast + Bs = 100352 bytes

__device__ __forceinline__ void grid_bar(unsigned* cnt, unsigned target) {
    __syncthreads();  // all WG stores drained to L2 (waitcnt before barrier)
    if (threadIdx.x == 0) {
        // release: wbl2 before the RMW makes this WG's stores device-visible
        __hip_atomic_fetch_add(cnt, 1u, __ATOMIC_RELEASE, __HIP_MEMORY_SCOPE_AGENT);
        while (__hip_atomic_load(cnt, __ATOMIC_RELAXED, __HIP_MEMORY_SCOPE_AGENT) < target)
            __builtin_amdgcn_s_sleep(1);
        __threadfence();  // acquire: invalidate L1/L2 so peers' writes are visible
    }
    __syncthreads();
}

__global__ __launch_bounds__(256, 1) void k_chain(
    const float* __restrict__ Whh_f, const float* __restrict__ Wih_f,
    const float* __restrict__ b_f, const float* __restrict__ Z0,
    float* __restrict__ h0_all, float* __restrict__ Pbuf, float* __restrict__ h1buf,
    unsigned* __restrict__ bar)
{
    extern __shared__ float smem[];
    float* Ast = smem;                        // [256][AST_STRIDE]  (k-major, m minor)
    float* Bs  = smem + 256 * AST_STRIDE;     // [256][64]          (k-major, n minor)

    const int tid  = threadIdx.x;
    const int wg   = blockIdx.x;   // 0..47
    const int role = wg >> 4;      // 16 WGs per role
    const int tile = wg & 15;
    const int m0 = (tile >> 2) * 32;
    const int n0 = (tile & 3) * 64;
    const int tx = tid & 15, ty = tid >> 4;

    // B-slice prefetch mapping: k = pk + 16*i, n = n0 + pn .. +3
    const int pk = tid >> 4;
    const int pn = (tid & 15) * 4;
    // A staging mapping: row ar, cols ac+32*i .. +3
    const int ar = tid >> 3;
    const int ac = (tid & 7) * 4;

    const size_t BH = (size_t)Bb * Hh;

    float4 pre[16];

    // weight pointer for the B-matrix consumed at step s (index clamped; out-of-
    // range steps stage harmless data that is never used)
    auto wclamp = [](int t) { return t < 0 ? 0 : (t > 255 ? 255 : t); };
    const float* W0;
    {
        int s = 0;
        const float* W =
            (role == 0) ? Whh_f + (size_t)wclamp(s) * Hh * Hh :
            (role == 1) ? Wih_f + (size_t)(Tt + wclamp(s - 1)) * Dd * Hh :
                          Whh_f + (size_t)(Tt + wclamp(s - 2)) * Hh * Hh;
        W0 = W;
    }
#pragma unroll
    for (int i = 0; i < 16; i++)
        pre[i] = *(const float4*)&W0[(size_t)(pk + 16 * i) * Hh + n0 + pn];

    for (int s = 0; s < NSTEP; ++s) {
        // ---- stage Bs from prefetched regs (weights for step s) ----
#pragma unroll
        for (int i = 0; i < 16; i++)
            *(float4*)&Bs[(size_t)(pk + 16 * i) * 64 + pn] = pre[i];

        // ---- issue prefetch for step s+1 ----
        {
            const float* W =
                (role == 0) ? Whh_f + (size_t)wclamp(s + 1) * Hh * Hh :
                (role == 1) ? Wih_f + (size_t)(Tt + wclamp(s)) * Dd * Hh :
                              Whh_f + (size_t)(Tt + wclamp(s - 1)) * Hh * Hh;
#pragma unroll
            for (int i = 0; i < 16; i++)
                pre[i] = *(const float4*)&W[(size_t)(pk + 16 * i) * Hh + n0 + pn];
        }

        // ---- role activity & A matrix ----
        const float* Amat = nullptr;
        bool active = false;
        if (role == 0) {
            active = (s < Tt);
            if (active && s > 0) Amat = h0_all + (size_t)(s - 1) * BH;
        } else if (role == 1) {
            active = (s >= 1 && s <= Tt);
            if (active) Amat = h0_all + (size_t)(s - 1) * BH;
        } else {
            active = (s >= 2);
            const int t = s - 2;
            if (active && t > 0) Amat = h1buf + (size_t)((t + 1) & 1) * BH;
        }

        // ---- stage A (transposed into Ast[k][m]) ----
        if (Amat) {
#pragma unroll
            for (int i = 0; i < 8; i++) {
                const float4 av = *(const float4*)&Amat[(size_t)(m0 + ar) * Hh + ac + 32 * i];
                Ast[(size_t)(ac + 32 * i + 0) * AST_STRIDE + ar] = av.x;
                Ast[(size_t)(ac + 32 * i + 1) * AST_STRIDE + ar] = av.y;
                Ast[(size_t)(ac + 32 * i + 2) * AST_STRIDE + ar] = av.z;
                Ast[(size_t)(ac + 32 * i + 3) * AST_STRIDE + ar] = av.w;
            }
        }
        __syncthreads();

        // ---- compute 32x64 tile, full K=256 ----
        float acc[2][4] = {{0.f, 0.f, 0.f, 0.f}, {0.f, 0.f, 0.f, 0.f}};
        if (Amat) {
#pragma unroll 8
            for (int kk = 0; kk < 256; kk++) {
                const float2 a = *(const float2*)&Ast[(size_t)kk * AST_STRIDE + ty * 2];
                const float4 b = *(const float4*)&Bs[(size_t)kk * 64 + tx * 4];
                acc[0][0] += a.x * b.x; acc[0][1] += a.x * b.y;
                acc[0][2] += a.x * b.z; acc[0][3] += a.x * b.w;
                acc[1][0] += a.y * b.x; acc[1][1] += a.y * b.y;
                acc[1][2] += a.y * b.z; acc[1][3] += a.y * b.w;
            }
        }

        // ---- epilogue ----
        if (active) {
            const float* addend = nullptr;
            const float* bias = nullptr;
            float* Cout;
            bool dot;
            if (role == 0) {
                addend = Z0 + (size_t)s * BH;
                Cout = h0_all + (size_t)s * BH;
                dot = true;
            } else if (role == 1) {
                const int t = s - 1;
                bias = b_f + (size_t)(Tt + t) * Hh;
                Cout = Pbuf + (size_t)(t & 1) * BH;
                dot = false;
            } else {
                const int t = s - 2;
                addend = Pbuf + (size_t)(t & 1) * BH;
                Cout = h1buf + (size_t)(t & 1) * BH;
                dot = true;
            }
#pragma unroll
            for (int i = 0; i < 2; i++) {
                const int m = m0 + ty * 2 + i;
                float4 v = make_float4(acc[i][0], acc[i][1], acc[i][2], acc[i][3]);
                if (addend) {
                    const float4 z = *(const float4*)&addend[(size_t)m * Hh + n0 + tx * 4];
                    v.x += z.x; v.y += z.y; v.z += z.z; v.w += z.w;
                }
                if (bias) {
                    const float4 bb = *(const float4*)&bias[n0 + tx * 4];
                    v.x += bb.x; v.y += bb.y; v.z += bb.z; v.w += bb.w;
                }
                if (dot) {
                    v.x = tanhf(v.x); v.y = tanhf(v.y);
                    v.z = tanhf(v.z); v.w = tanhf(v.w);
                }
                *(float4*)&Cout[(size_t)m * Hh + n0 + tx * 4] = v;
            }
        }

        grid_bar(bar, (unsigned)((s + 1) * GWG));
    }
}

__global__ void k_zero(unsigned* c) {
    if (threadIdx.x == 0)
        __hip_atomic_store(c, 0u, __ATOMIC_RELEASE, __HIP_MEMORY_SCOPE_AGENT);
}

// out[b][h] = h1fin[b]·fc_w[h][0:256] + hb1[b]·fc_w[h][256:512] + fc_b[h]
__global__ void k_fc(const float* __restrict__ h1fin, const float* __restrict__ hb1,
                     const float* __restrict__ fcw, const float* __restrict__ fcb,
                     float* __restrict__ out) {
    const int b = blockIdx.x;
    const int h = threadIdx.x;  // 256
    __shared__ float last[2 * Hh];
    last[h] = h1fin[(size_t)b * Hh + h];
    last[Hh + h] = hb1[(size_t)b * Hh + h];
    __syncthreads();
    float acc = fcb[h];
    const float* wrow = fcw + (size_t)h * (2 * Hh);
#pragma unroll 4
    for (int j = 0; j < 2 * Hh; j++) acc += last[j] * wrow[j];
    out[(size_t)b * Hh + h] = acc;
}

extern "C" void kernel_launch(void* const* d_in, const int* in_sizes, int n_in,
                              void* d_out, int out_size, void* d_ws, size_t ws_size,
                              hipStream_t stream) {
    const float* x     = (const float*)d_in[0];
    const float* Wih_f = (const float*)d_in[1];
    const float* Whh_f = (const float*)d_in[2];
    const float* b_f   = (const float*)d_in[3];
    const float* Wih_b = (const float*)d_in[4];
    // d_in[5] = Whh_b: provably unused
    const float* b_b   = (const float*)d_in[6];
    const float* fc_w  = (const float*)d_in[7];
    const float* fc_b  = (const float*)d_in[8];
    float* out = (float*)d_out;

    // ws layout (floats): Z0[T*B*H] | h0_all[T*B*H] | Pbuf[2BH] | h1buf[2BH] | hb0 | hb1 | counter
    float* ws     = (float*)d_ws;
    float* Z0     = ws;
    float* h0_all = Z0 + (size_t)Tt * Bb * Hh;
    float* Pbuf   = h0_all + (size_t)Tt * Bb * Hh;
    float* h1buf  = Pbuf + (size_t)2 * Bb * Hh;
    float* hb0    = h1buf + (size_t)2 * Bb * Hh;
    float* hb1    = hb0 + (size_t)Bb * Hh;
    unsigned* bar = (unsigned*)(hb1 + (size_t)Bb * Hh);

    dim3 blk(256);
    hipLaunchKernelGGL(k_z0, dim3(16, Tt), blk, 0, stream, x, Wih_f, b_f, Z0);
    hipLaunchKernelGGL(k_back0, dim3(16), blk, 0, stream, x, Wih_b, b_b, hb0);
    hipLaunchKernelGGL(k_back1, dim3(16), blk, 0, stream, hb0, Wih_b, b_b, hb1);
    hipLaunchKernelGGL(k_zero, dim3(1), dim3(64), 0, stream, bar);
    hipLaunchKernelGGL(k_chain, dim3(GWG), blk, LDS_FLOATS * sizeof(float), stream,
                       Whh_f, Wih_f, b_f, Z0, h0_all, Pbuf, h1buf, bar);
    // h1(T-1) is in h1buf[ (T-1)&1 ] = h1buf[1]
    hipLaunchKernelGGL(k_fc, dim3(Bb), blk, 0, stream,
                       h1buf + (size_t)1 * Bb * Hh, hb1, fc_w, fc_b, out);
}